// Round 2
// baseline (2927.296 us; speedup 1.0000x reference)
//
#include <hip/hip_runtime.h>
#include <cstdint>

#define B_ 2
#define N_ 50000
#define D_ 128
#define E_ 800000
#define TOK 100000   // B_*N_

typedef __bf16 bf16x8 __attribute__((ext_vector_type(8)));
typedef float f32x4 __attribute__((ext_vector_type(4)));

__device__ __forceinline__ unsigned short f2bf(float f) {
  union { float f; uint32_t u; } v; v.f = f;
  uint32_t u = v.u;
  return (unsigned short)((u + 0x7FFFu + ((u >> 16) & 1u)) >> 16);
}

// ---------------- scatter-add: neighbor[b,dst,:] += x[b,src,:] (fp32) -------
// 32 threads per edge, 4 consecutive floats each, both batches.
__global__ __launch_bounds__(256) void scatter_k(
    const float* __restrict__ x, const int* __restrict__ esrc,
    const int* __restrict__ edst, float* __restrict__ nb) {
  int t = blockIdx.x * 256 + threadIdx.x;   // E_*32 threads exactly
  int e = t >> 5;
  int off = (t & 31) << 2;
  int s = esrc[e], d = edst[e];
#pragma unroll
  for (int b = 0; b < B_; ++b) {
    const float4 v = *(const float4*)(x + ((size_t)b * N_ + s) * D_ + off);
    float* o = nb + ((size_t)b * N_ + d) * D_ + off;
    atomicAdd(o + 0, v.x);
    atomicAdd(o + 1, v.y);
    atomicAdd(o + 2, v.z);
    atomicAdd(o + 3, v.w);
  }
}

// ---------------- fused dual LayerNorm -> h = [LN(x), LN(nb/deg)] bf16 ------
__global__ __launch_bounds__(256) void ln_k(
    const float* __restrict__ x, const float* __restrict__ nb,
    const float* __restrict__ degree,
    const float* __restrict__ sn_g, const float* __restrict__ sn_b,
    const float* __restrict__ nn_g, const float* __restrict__ nn_b,
    unsigned short* __restrict__ h) {
  int wid = (blockIdx.x * 256 + threadIdx.x) >> 6;  // one wave per token row
  int lane = threadIdx.x & 63;
  int node = wid % N_;
  float2 xv = *(const float2*)(x + (size_t)wid * D_ + lane * 2);
  float2 nv = *(const float2*)(nb + (size_t)wid * D_ + lane * 2);
  float inv = 1.0f / fmaxf(degree[node], 1.0f);
  float n0v = nv.x * inv, n1v = nv.y * inv;
  float sx = xv.x + xv.y, sxx = xv.x * xv.x + xv.y * xv.y;
  float sn = n0v + n1v, snn = n0v * n0v + n1v * n1v;
#pragma unroll
  for (int off = 32; off; off >>= 1) {
    sx  += __shfl_xor(sx, off);  sxx += __shfl_xor(sxx, off);
    sn  += __shfl_xor(sn, off);  snn += __shfl_xor(snn, off);
  }
  const float r = 1.0f / 128.0f;
  float mx = sx * r, vx = fmaxf(sxx * r - mx * mx, 0.f);
  float mn = sn * r, vn = fmaxf(snn * r - mn * mn, 0.f);
  float rx = rsqrtf(vx + 1e-5f), rn = rsqrtf(vn + 1e-5f);
  int c = lane * 2;
  float y0 = (xv.x - mx) * rx * sn_g[c]     + sn_b[c];
  float y1 = (xv.y - mx) * rx * sn_g[c + 1] + sn_b[c + 1];
  float z0 = (n0v - mn) * rn * nn_g[c]     + nn_b[c];
  float z1 = (n1v - mn) * rn * nn_g[c + 1] + nn_b[c + 1];
  unsigned short* hr = h + (size_t)wid * 256;
  *(uint32_t*)(hr + c)       = (uint32_t)f2bf(y0) | ((uint32_t)f2bf(y1) << 16);
  *(uint32_t*)(hr + 128 + c) = (uint32_t)f2bf(z0) | ((uint32_t)f2bf(z1) << 16);
}

// ---------------- weight transpose to bf16 [n][k] ---------------------------
__global__ __launch_bounds__(256) void prep_w_k(
    const float* __restrict__ W1, const float* __restrict__ W2,
    unsigned short* __restrict__ W1t, unsigned short* __restrict__ W2t) {
  int t = blockIdx.x * 256 + threadIdx.x;
  if (t < 65536) {
    int n = t >> 8, k = t & 255;
    W1t[t] = f2bf(W1[k * 256 + n]);
  } else if (t < 65536 + 32768) {
    int t2 = t - 65536;
    int n = t2 >> 8, k = t2 & 255;
    W2t[t2] = f2bf(W2[k * 128 + n]);
  }
}

// ---------------- MFMA GEMM: out = act(A @ Wt^T + bias) [+ resid] -----------
// A [M][256] bf16(u16), Wt [Ntot][256] bf16. Tile 128x128, BK=64, 4 waves
// (2x2), each wave 64x64 via 4x4 grid of 16x16x32 mfma.
template<bool GELU, bool RES>
__global__ __launch_bounds__(256, 2) void gemm_k(
    const unsigned short* __restrict__ A,
    const unsigned short* __restrict__ Wt,
    const float* __restrict__ bias,
    const float* __restrict__ resid,
    void* __restrict__ outp, int M) {
  constexpr int LDA = 72;  // +8 bf16 pad (16B) -> 144B row stride, 16B aligned
  __shared__ unsigned short As[128 * LDA];
  __shared__ unsigned short Bs[128 * LDA];
  const int tid = threadIdx.x;
  const int wave = tid >> 6, lane = tid & 63;
  const int wr = wave >> 1, wc = wave & 1;
  const int quad = lane >> 4, l15 = lane & 15;
  const int m0 = blockIdx.x * 128, n0 = blockIdx.y * 128;
  f32x4 acc[4][4] = {};
  for (int kb = 0; kb < 256; kb += 64) {
#pragma unroll
    for (int c = 0; c < 4; ++c) {
      int idx = c * 256 + tid;
      int row = idx >> 3, c8 = (idx & 7) << 3;
      int gm = m0 + row;
      uint4 va = {0u, 0u, 0u, 0u};
      if (gm < M) va = *(const uint4*)(A + (size_t)gm * 256 + kb + c8);
      *(uint4*)(&As[row * LDA + c8]) = va;
      uint4 vb = *(const uint4*)(Wt + (size_t)(n0 + row) * 256 + kb + c8);
      *(uint4*)(&Bs[row * LDA + c8]) = vb;
    }
    __syncthreads();
#pragma unroll
    for (int kc = 0; kc < 64; kc += 32) {
      bf16x8 a[4], b[4];
#pragma unroll
      for (int i = 0; i < 4; ++i) {
        a[i] = *(const bf16x8*)(&As[(wr * 64 + i * 16 + l15) * LDA + kc + quad * 8]);
        b[i] = *(const bf16x8*)(&Bs[(wc * 64 + i * 16 + l15) * LDA + kc + quad * 8]);
      }
#pragma unroll
      for (int mi = 0; mi < 4; ++mi)
#pragma unroll
        for (int ni = 0; ni < 4; ++ni)
          acc[mi][ni] = __builtin_amdgcn_mfma_f32_16x16x32_bf16(a[mi], b[ni], acc[mi][ni], 0, 0, 0);
    }
    __syncthreads();
  }
  // epilogue: D row = quad*4 + reg, col = l15 (within each 16x16)
#pragma unroll
  for (int mi = 0; mi < 4; ++mi) {
#pragma unroll
    for (int ni = 0; ni < 4; ++ni) {
      int col = n0 + wc * 64 + ni * 16 + l15;
      float bv = bias[col];
#pragma unroll
      for (int rr = 0; rr < 4; ++rr) {
        int row = m0 + wr * 64 + mi * 16 + quad * 4 + rr;
        if (row < M) {
          float v = acc[mi][ni][rr] + bv;
          if (GELU) {
            v = 0.5f * v * (1.0f + erff(v * 0.70710678118654752f));
            ((unsigned short*)outp)[(size_t)row * 256 + col] = f2bf(v);
          }
          if (RES) {
            float xr = resid[(size_t)row * 128 + col];
            ((float*)outp)[(size_t)row * 128 + col] = xr + v;
          }
        }
      }
    }
  }
}

extern "C" void kernel_launch(void* const* d_in, const int* in_sizes, int n_in,
                              void* d_out, int out_size, void* d_ws, size_t ws_size,
                              hipStream_t stream) {
  const float* x    = (const float*)d_in[0];
  const int* esrc   = (const int*)d_in[1];
  const int* edst   = (const int*)d_in[2];
  const float* deg  = (const float*)d_in[3];
  const float* sn_g = (const float*)d_in[4];
  const float* sn_b = (const float*)d_in[5];
  const float* nn_g = (const float*)d_in[6];
  const float* nn_b = (const float*)d_in[7];
  const float* W1   = (const float*)d_in[8];
  const float* b1   = (const float*)d_in[9];
  const float* W2   = (const float*)d_in[10];
  const float* b2   = (const float*)d_in[11];

  char* ws = (char*)d_ws;
  const size_t NB_BYTES = (size_t)B_ * N_ * D_ * sizeof(float);  // 51.2 MB
  float* nb = (float*)ws;                                   // [B,N,D] fp32 accum
  unsigned short* h  = (unsigned short*)(ws + NB_BYTES);    // [TOK][256] bf16
  unsigned short* h1 = (unsigned short*)ws;                 // alias nb (dead after ln)
  unsigned short* W1t = (unsigned short*)(ws + 2 * NB_BYTES);
  unsigned short* W2t = W1t + 65536;

  hipMemsetAsync(nb, 0, NB_BYTES, stream);
  prep_w_k<<<(98304 + 255) / 256, 256, 0, stream>>>(W1, W2, W1t, W2t);
  scatter_k<<<(E_ * 32) / 256, 256, 0, stream>>>(x, esrc, edst, nb);
  ln_k<<<TOK / 4, 256, 0, stream>>>(x, nb, deg, sn_g, sn_b, nn_g, nn_b, h);
  dim3 g1((TOK + 127) / 128, 2);
  gemm_k<true, false><<<g1, 256, 0, stream>>>(h, W1t, b1, nullptr, h1, TOK);
  dim3 g2((TOK + 127) / 128, 1);
  gemm_k<false, true><<<g2, 256, 0, stream>>>(h1, W2t, b2, x, d_out, TOK);
}

// Round 3
// 468.238 us; speedup vs baseline: 6.2517x; 6.2517x over previous
//
#include <hip/hip_runtime.h>
#include <cstdint>

#define B_ 2
#define N_ 50000
#define D_ 128
#define E_ 800000
#define TOK 100000   // B_*N_

typedef __bf16 bf16x8 __attribute__((ext_vector_type(8)));
typedef float f32x4 __attribute__((ext_vector_type(4)));

__device__ __forceinline__ unsigned short f2bf(float f) {
  union { float f; uint32_t u; } v; v.f = f;
  uint32_t u = v.u;
  return (unsigned short)((u + 0x7FFFu + ((u >> 16) & 1u)) >> 16);
}

// ---------------- CSR build: histogram of edge_dst --------------------------
__global__ __launch_bounds__(256) void hist_k(const int* __restrict__ edst,
                                              int* __restrict__ cnt) {
  int e = blockIdx.x * 256 + threadIdx.x;
  if (e < E_) atomicAdd(&cnt[edst[e]], 1);
}

// ---------------- CSR build: single-block exclusive scan --------------------
__global__ __launch_bounds__(1024) void scan_k(const int* __restrict__ cnt,
                                               int* __restrict__ rs,
                                               int* __restrict__ cursor) {
  __shared__ int wsum[16];
  __shared__ int woff[16];
  __shared__ int carry_s;
  const int tid = threadIdx.x, lane = tid & 63, wv = tid >> 6;
  if (tid == 0) carry_s = 0;
  __syncthreads();
  for (int base = 0; base < N_; base += 1024) {
    int i = base + tid;
    int v = (i < N_) ? cnt[i] : 0;
    int s = v;
#pragma unroll
    for (int off = 1; off < 64; off <<= 1) {
      int t = __shfl_up(s, off);
      if (lane >= off) s += t;
    }
    if (lane == 63) wsum[wv] = s;
    int carry = carry_s;
    __syncthreads();
    if (tid == 0) {
      int acc = 0;
#pragma unroll
      for (int w = 0; w < 16; ++w) { woff[w] = acc; acc += wsum[w]; }
      carry_s = carry + acc;
    }
    __syncthreads();
    int excl = carry + woff[wv] + (s - v);
    if (i < N_) { rs[i] = excl; cursor[i] = excl; }
    __syncthreads();
  }
  if (tid == 0) rs[N_] = carry_s;   // == E_
}

// ---------------- CSR build: counting-sort edge srcs by dst -----------------
__global__ __launch_bounds__(256) void fill_k(const int* __restrict__ esrc,
                                              const int* __restrict__ edst,
                                              int* __restrict__ cursor,
                                              int* __restrict__ sorted_src) {
  int e = blockIdx.x * 256 + threadIdx.x;
  if (e < E_) {
    int pos = atomicAdd(&cursor[edst[e]], 1);
    sorted_src[pos] = esrc[e];
  }
}

// ---------------- fused gather + dual LayerNorm -> h = [LN(x), LN(nb)] -----
// One wave per (node, batch): register-sum in-edges, then LN both halves.
__global__ __launch_bounds__(256) void gather_ln_k(
    const float* __restrict__ x, const int* __restrict__ rs,
    const int* __restrict__ sorted_src,
    const float* __restrict__ sn_g, const float* __restrict__ sn_b,
    const float* __restrict__ nn_g, const float* __restrict__ nn_b,
    unsigned short* __restrict__ h) {
  const int wid = blockIdx.x * 4 + (threadIdx.x >> 6);  // 0..2*N_-1
  const int lane = threadIdx.x & 63;
  const int node = wid >> 1, b = wid & 1;
  const int r0 = rs[node], r1 = rs[node + 1];
  const float2* xb = (const float2*)(x + (size_t)b * N_ * D_);
  float2 acc = {0.f, 0.f};
  int e = r0;
  for (; e + 4 <= r1; e += 4) {
    int s0 = sorted_src[e], s1 = sorted_src[e + 1];
    int s2 = sorted_src[e + 2], s3 = sorted_src[e + 3];
    float2 v0 = xb[(size_t)s0 * 64 + lane];
    float2 v1 = xb[(size_t)s1 * 64 + lane];
    float2 v2 = xb[(size_t)s2 * 64 + lane];
    float2 v3 = xb[(size_t)s3 * 64 + lane];
    acc.x += (v0.x + v1.x) + (v2.x + v3.x);
    acc.y += (v0.y + v1.y) + (v2.y + v3.y);
  }
  for (; e < r1; ++e) {
    float2 v = xb[(size_t)sorted_src[e] * 64 + lane];
    acc.x += v.x; acc.y += v.y;
  }
  const float inv = 1.0f / fmaxf((float)(r1 - r0), 1.0f);
  float n0v = acc.x * inv, n1v = acc.y * inv;
  float2 xv = xb[(size_t)node * 64 + lane];
  float sx = xv.x + xv.y, sxx = xv.x * xv.x + xv.y * xv.y;
  float sn = n0v + n1v, snn = n0v * n0v + n1v * n1v;
#pragma unroll
  for (int off = 32; off; off >>= 1) {
    sx  += __shfl_xor(sx, off);  sxx += __shfl_xor(sxx, off);
    sn  += __shfl_xor(sn, off);  snn += __shfl_xor(snn, off);
  }
  const float r = 1.0f / 128.0f;
  float mx = sx * r, vx = fmaxf(sxx * r - mx * mx, 0.f);
  float mn = sn * r, vn = fmaxf(snn * r - mn * mn, 0.f);
  float rx = rsqrtf(vx + 1e-5f), rn = rsqrtf(vn + 1e-5f);
  int c = lane * 2;
  float y0 = (xv.x - mx) * rx * sn_g[c]     + sn_b[c];
  float y1 = (xv.y - mx) * rx * sn_g[c + 1] + sn_b[c + 1];
  float z0 = (n0v - mn) * rn * nn_g[c]     + nn_b[c];
  float z1 = (n1v - mn) * rn * nn_g[c + 1] + nn_b[c + 1];
  unsigned short* hr = h + ((size_t)b * N_ + node) * 256;
  *(uint32_t*)(hr + c)       = (uint32_t)f2bf(y0) | ((uint32_t)f2bf(y1) << 16);
  *(uint32_t*)(hr + 128 + c) = (uint32_t)f2bf(z0) | ((uint32_t)f2bf(z1) << 16);
}

// ---------------- weight transpose to bf16 [n][k] ---------------------------
__global__ __launch_bounds__(256) void prep_w_k(
    const float* __restrict__ W1, const float* __restrict__ W2,
    unsigned short* __restrict__ W1t, unsigned short* __restrict__ W2t) {
  int t = blockIdx.x * 256 + threadIdx.x;
  if (t < 65536) {
    int n = t >> 8, k = t & 255;
    W1t[t] = f2bf(W1[k * 256 + n]);
  } else if (t < 65536 + 32768) {
    int t2 = t - 65536;
    int n = t2 >> 8, k = t2 & 255;
    W2t[t2] = f2bf(W2[k * 128 + n]);
  }
}

// ---------------- MFMA GEMM: out = act(A @ Wt^T + bias) [+ resid] -----------
template<bool GELU, bool RES>
__global__ __launch_bounds__(256, 2) void gemm_k(
    const unsigned short* __restrict__ A,
    const unsigned short* __restrict__ Wt,
    const float* __restrict__ bias,
    const float* __restrict__ resid,
    void* __restrict__ outp, int M) {
  constexpr int LDA = 72;
  __shared__ unsigned short As[128 * LDA];
  __shared__ unsigned short Bs[128 * LDA];
  const int tid = threadIdx.x;
  const int wave = tid >> 6, lane = tid & 63;
  const int wr = wave >> 1, wc = wave & 1;
  const int quad = lane >> 4, l15 = lane & 15;
  const int m0 = blockIdx.x * 128, n0 = blockIdx.y * 128;
  f32x4 acc[4][4] = {};
  for (int kb = 0; kb < 256; kb += 64) {
#pragma unroll
    for (int c = 0; c < 4; ++c) {
      int idx = c * 256 + tid;
      int row = idx >> 3, c8 = (idx & 7) << 3;
      int gm = m0 + row;
      uint4 va = {0u, 0u, 0u, 0u};
      if (gm < M) va = *(const uint4*)(A + (size_t)gm * 256 + kb + c8);
      *(uint4*)(&As[row * LDA + c8]) = va;
      uint4 vb = *(const uint4*)(Wt + (size_t)(n0 + row) * 256 + kb + c8);
      *(uint4*)(&Bs[row * LDA + c8]) = vb;
    }
    __syncthreads();
#pragma unroll
    for (int kc = 0; kc < 64; kc += 32) {
      bf16x8 a[4], b[4];
#pragma unroll
      for (int i = 0; i < 4; ++i) {
        a[i] = *(const bf16x8*)(&As[(wr * 64 + i * 16 + l15) * LDA + kc + quad * 8]);
        b[i] = *(const bf16x8*)(&Bs[(wc * 64 + i * 16 + l15) * LDA + kc + quad * 8]);
      }
#pragma unroll
      for (int mi = 0; mi < 4; ++mi)
#pragma unroll
        for (int ni = 0; ni < 4; ++ni)
          acc[mi][ni] = __builtin_amdgcn_mfma_f32_16x16x32_bf16(a[mi], b[ni], acc[mi][ni], 0, 0, 0);
    }
    __syncthreads();
  }
#pragma unroll
  for (int mi = 0; mi < 4; ++mi) {
#pragma unroll
    for (int ni = 0; ni < 4; ++ni) {
      int col = n0 + wc * 64 + ni * 16 + l15;
      float bv = bias[col];
#pragma unroll
      for (int rr = 0; rr < 4; ++rr) {
        int row = m0 + wr * 64 + mi * 16 + quad * 4 + rr;
        if (row < M) {
          float v = acc[mi][ni][rr] + bv;
          if (GELU) {
            v = 0.5f * v * (1.0f + erff(v * 0.70710678118654752f));
            ((unsigned short*)outp)[(size_t)row * 256 + col] = f2bf(v);
          }
          if (RES) {
            float xr = resid[(size_t)row * 128 + col];
            ((float*)outp)[(size_t)row * 128 + col] = xr + v;
          }
        }
      }
    }
  }
}

extern "C" void kernel_launch(void* const* d_in, const int* in_sizes, int n_in,
                              void* d_out, int out_size, void* d_ws, size_t ws_size,
                              hipStream_t stream) {
  const float* x    = (const float*)d_in[0];
  const int* esrc   = (const int*)d_in[1];
  const int* edst   = (const int*)d_in[2];
  const float* sn_g = (const float*)d_in[4];
  const float* sn_b = (const float*)d_in[5];
  const float* nn_g = (const float*)d_in[6];
  const float* nn_b = (const float*)d_in[7];
  const float* W1   = (const float*)d_in[8];
  const float* b1   = (const float*)d_in[9];
  const float* W2   = (const float*)d_in[10];
  const float* b2   = (const float*)d_in[11];

  char* ws = (char*)d_ws;
  const size_t H_BYTES = (size_t)TOK * 256 * 2;          // 51.2 MB
  unsigned short* h  = (unsigned short*)ws;              // [TOK][256] bf16
  // CSR region (dead before gemm1) overlapped by h1:
  int* cnt        = (int*)(ws + H_BYTES);                // N_ ints
  int* rs         = (int*)(ws + H_BYTES + 200000);       // N_+1 ints
  int* cursor     = (int*)(ws + H_BYTES + 400016);       // N_ ints
  int* sorted_src = (int*)(ws + H_BYTES + 600016);       // E_ ints (3.2 MB)
  unsigned short* h1 = (unsigned short*)(ws + H_BYTES);  // [TOK][256] bf16 (aliases CSR)
  unsigned short* W1t = (unsigned short*)(ws + 2 * H_BYTES);
  unsigned short* W2t = W1t + 65536;

  hipMemsetAsync(cnt, 0, (size_t)N_ * sizeof(int), stream);
  prep_w_k<<<(98304 + 255) / 256, 256, 0, stream>>>(W1, W2, W1t, W2t);
  hist_k<<<(E_ + 255) / 256, 256, 0, stream>>>(edst, cnt);
  scan_k<<<1, 1024, 0, stream>>>(cnt, rs, cursor);
  fill_k<<<(E_ + 255) / 256, 256, 0, stream>>>(esrc, edst, cursor, sorted_src);
  gather_ln_k<<<(2 * N_) / 4, 256, 0, stream>>>(x, rs, sorted_src,
                                                sn_g, sn_b, nn_g, nn_b, h);
  dim3 g1((TOK + 127) / 128, 2);
  gemm_k<true, false><<<g1, 256, 0, stream>>>(h, W1t, b1, nullptr, h1, TOK);
  dim3 g2((TOK + 127) / 128, 1);
  gemm_k<false, true><<<g2, 256, 0, stream>>>(h1, W2t, b2, x, d_out, TOK);
}

// Round 4
// 434.764 us; speedup vs baseline: 6.7331x; 1.0770x over previous
//
#include <hip/hip_runtime.h>
#include <cstdint>

#define B_ 2
#define N_ 50000
#define D_ 128
#define E_ 800000
#define TOK 100000   // B_*N_

typedef __bf16 bf16x8 __attribute__((ext_vector_type(8)));
typedef float f32x4 __attribute__((ext_vector_type(4)));

__device__ __forceinline__ unsigned short f2bf(float f) {
  union { float f; uint32_t u; } v; v.f = f;
  uint32_t u = v.u;
  return (unsigned short)((u + 0x7FFFu + ((u >> 16) & 1u)) >> 16);
}

// ---------------- CSR build: histogram of edge_dst --------------------------
__global__ __launch_bounds__(256) void hist_k(const int* __restrict__ edst,
                                              int* __restrict__ cnt) {
  int e = blockIdx.x * 256 + threadIdx.x;
  if (e < E_) atomicAdd(&cnt[edst[e]], 1);
}

// ---------------- hierarchical scan: phase 1 (block-local) ------------------
__global__ __launch_bounds__(1024) void scan1_k(const int* __restrict__ cnt,
                                                int* __restrict__ part,
                                                int* __restrict__ bsum) {
  __shared__ int wsum[16], woff[16];
  const int tid = threadIdx.x, lane = tid & 63, wv = tid >> 6;
  int i = blockIdx.x * 1024 + tid;
  int v = (i < N_) ? cnt[i] : 0;
  int s = v;
#pragma unroll
  for (int off = 1; off < 64; off <<= 1) {
    int t = __shfl_up(s, off);
    if (lane >= off) s += t;
  }
  if (lane == 63) wsum[wv] = s;
  __syncthreads();
  if (tid == 0) {
    int a = 0;
#pragma unroll
    for (int w = 0; w < 16; ++w) { woff[w] = a; a += wsum[w]; }
    bsum[blockIdx.x] = a;
  }
  __syncthreads();
  if (i < N_) part[i] = woff[wv] + s - v;
}

// ---------------- phase 2: scan the 49 block sums (one wave) ----------------
__global__ __launch_bounds__(64) void scan2_k(const int* __restrict__ bsum,
                                              int* __restrict__ boff) {
  int lane = threadIdx.x;
  int v = (lane < 49) ? bsum[lane] : 0;
  int s = v;
#pragma unroll
  for (int off = 1; off < 64; off <<= 1) {
    int t = __shfl_up(s, off);
    if (lane >= off) s += t;
  }
  boff[lane] = s - v;
}

// ---------------- phase 3: add block offsets, write rs + cursor -------------
__global__ __launch_bounds__(1024) void scan3_k(const int* __restrict__ part,
                                                const int* __restrict__ boff,
                                                int* __restrict__ rs,
                                                int* __restrict__ cursor) {
  int i = blockIdx.x * 1024 + threadIdx.x;
  if (i < N_) {
    int v = part[i] + boff[blockIdx.x];
    rs[i] = v; cursor[i] = v;
  }
  if (i == 0) rs[N_] = E_;
}

// ---------------- CSR build: counting-sort edge srcs by dst -----------------
__global__ __launch_bounds__(256) void fill_k(const int* __restrict__ esrc,
                                              const int* __restrict__ edst,
                                              int* __restrict__ cursor,
                                              int* __restrict__ sorted_src) {
  int e = blockIdx.x * 256 + threadIdx.x;
  if (e < E_) {
    int pos = atomicAdd(&cursor[edst[e]], 1);
    sorted_src[pos] = esrc[e];
  }
}

// ---------------- fused gather + dual LayerNorm -> h = [LN(x), LN(nb)] -----
// One wave per node; half-wave = batch. Lane covers 4 floats of the row.
__global__ __launch_bounds__(256) void gather_ln_k(
    const float* __restrict__ x, const int* __restrict__ rs,
    const int* __restrict__ sorted_src,
    const float* __restrict__ sn_g, const float* __restrict__ sn_b,
    const float* __restrict__ nn_g, const float* __restrict__ nn_b,
    unsigned short* __restrict__ h) {
  const int node = blockIdx.x * 4 + (threadIdx.x >> 6);   // grid exact: 50000
  const int lane = threadIdx.x & 63;
  const int half = lane >> 5;        // batch index
  const int l32 = lane & 31;         // 4-float chunk within row
  const int r0 = rs[node], r1 = rs[node + 1];
  const float* xb = x + (size_t)half * (N_ * D_) + l32 * 4;
  float ax = 0.f, ay = 0.f, az = 0.f, aw = 0.f;
  for (int e = r0; e < r1; e += 8) {
#pragma unroll
    for (int j = 0; j < 8; ++j) {
      int ej = e + j;
      int idx = sorted_src[(ej < r1) ? ej : r0];
      float4 v = *(const float4*)(xb + (size_t)idx * D_);
      if (ej < r1) { ax += v.x; ay += v.y; az += v.z; aw += v.w; }
    }
  }
  const float invd = 1.0f / fmaxf((float)(r1 - r0), 1.0f);
  float n0 = ax * invd, n1 = ay * invd, n2 = az * invd, n3 = aw * invd;
  float4 xv = *(const float4*)(xb + (size_t)node * D_);
  float sx = (xv.x + xv.y) + (xv.z + xv.w);
  float sxx = (xv.x * xv.x + xv.y * xv.y) + (xv.z * xv.z + xv.w * xv.w);
  float sn = (n0 + n1) + (n2 + n3);
  float snn = (n0 * n0 + n1 * n1) + (n2 * n2 + n3 * n3);
#pragma unroll
  for (int off = 1; off < 32; off <<= 1) {   // stays within the 32-lane half
    sx  += __shfl_xor(sx, off);  sxx += __shfl_xor(sxx, off);
    sn  += __shfl_xor(sn, off);  snn += __shfl_xor(snn, off);
  }
  const float r = 1.0f / 128.0f;
  float mx = sx * r, vx = fmaxf(sxx * r - mx * mx, 0.f);
  float mn = sn * r, vn = fmaxf(snn * r - mn * mn, 0.f);
  float rx = rsqrtf(vx + 1e-5f), rn = rsqrtf(vn + 1e-5f);
  int c = l32 * 4;
  float4 g1v = *(const float4*)(sn_g + c), b1v = *(const float4*)(sn_b + c);
  float4 g2v = *(const float4*)(nn_g + c), b2v = *(const float4*)(nn_b + c);
  float y0 = (xv.x - mx) * rx * g1v.x + b1v.x;
  float y1 = (xv.y - mx) * rx * g1v.y + b1v.y;
  float y2 = (xv.z - mx) * rx * g1v.z + b1v.z;
  float y3 = (xv.w - mx) * rx * g1v.w + b1v.w;
  float z0 = (n0 - mn) * rn * g2v.x + b2v.x;
  float z1 = (n1 - mn) * rn * g2v.y + b2v.y;
  float z2 = (n2 - mn) * rn * g2v.z + b2v.z;
  float z3 = (n3 - mn) * rn * g2v.w + b2v.w;
  unsigned short* hr = h + ((size_t)half * N_ + node) * 256;
  uint2 py = { (uint32_t)f2bf(y0) | ((uint32_t)f2bf(y1) << 16),
               (uint32_t)f2bf(y2) | ((uint32_t)f2bf(y3) << 16) };
  uint2 pz = { (uint32_t)f2bf(z0) | ((uint32_t)f2bf(z1) << 16),
               (uint32_t)f2bf(z2) | ((uint32_t)f2bf(z3) << 16) };
  *(uint2*)(hr + c)       = py;
  *(uint2*)(hr + 128 + c) = pz;
}

// ---------------- weight transpose to bf16 [n][k] ---------------------------
__global__ __launch_bounds__(256) void prep_w_k(
    const float* __restrict__ W1, const float* __restrict__ W2,
    unsigned short* __restrict__ W1t, unsigned short* __restrict__ W2t) {
  int t = blockIdx.x * 256 + threadIdx.x;
  if (t < 65536) {
    int n = t >> 8, k = t & 255;
    W1t[t] = f2bf(W1[k * 256 + n]);
  } else if (t < 65536 + 32768) {
    int t2 = t - 65536;
    int n = t2 >> 8, k = t2 & 255;
    W2t[t2] = f2bf(W2[k * 128 + n]);
  }
}

// ---------------- MFMA GEMM: out = act(A @ Wt^T + bias) [+ resid] -----------
template<bool GELU, bool RES>
__global__ __launch_bounds__(256, 2) void gemm_k(
    const unsigned short* __restrict__ A,
    const unsigned short* __restrict__ Wt,
    const float* __restrict__ bias,
    const float* __restrict__ resid,
    void* __restrict__ outp, int M) {
  constexpr int LDA = 72;
  __shared__ unsigned short As[128 * LDA];
  __shared__ unsigned short Bs[128 * LDA];
  const int tid = threadIdx.x;
  const int wave = tid >> 6, lane = tid & 63;
  const int wr = wave >> 1, wc = wave & 1;
  const int quad = lane >> 4, l15 = lane & 15;
  const int m0 = blockIdx.x * 128, n0 = blockIdx.y * 128;
  f32x4 acc[4][4] = {};
  for (int kb = 0; kb < 256; kb += 64) {
#pragma unroll
    for (int c = 0; c < 4; ++c) {
      int idx = c * 256 + tid;
      int row = idx >> 3, c8 = (idx & 7) << 3;
      int gm = m0 + row;
      uint4 va = {0u, 0u, 0u, 0u};
      if (gm < M) va = *(const uint4*)(A + (size_t)gm * 256 + kb + c8);
      *(uint4*)(&As[row * LDA + c8]) = va;
      uint4 vb = *(const uint4*)(Wt + (size_t)(n0 + row) * 256 + kb + c8);
      *(uint4*)(&Bs[row * LDA + c8]) = vb;
    }
    __syncthreads();
#pragma unroll
    for (int kc = 0; kc < 64; kc += 32) {
      bf16x8 a[4], b[4];
#pragma unroll
      for (int i = 0; i < 4; ++i) {
        a[i] = *(const bf16x8*)(&As[(wr * 64 + i * 16 + l15) * LDA + kc + quad * 8]);
        b[i] = *(const bf16x8*)(&Bs[(wc * 64 + i * 16 + l15) * LDA + kc + quad * 8]);
      }
#pragma unroll
      for (int mi = 0; mi < 4; ++mi)
#pragma unroll
        for (int ni = 0; ni < 4; ++ni)
          acc[mi][ni] = __builtin_amdgcn_mfma_f32_16x16x32_bf16(a[mi], b[ni], acc[mi][ni], 0, 0, 0);
    }
    __syncthreads();
  }
#pragma unroll
  for (int mi = 0; mi < 4; ++mi) {
#pragma unroll
    for (int ni = 0; ni < 4; ++ni) {
      int col = n0 + wc * 64 + ni * 16 + l15;
      float bv = bias[col];
#pragma unroll
      for (int rr = 0; rr < 4; ++rr) {
        int row = m0 + wr * 64 + mi * 16 + quad * 4 + rr;
        if (row < M) {
          float v = acc[mi][ni][rr] + bv;
          if (GELU) {
            v = 0.5f * v * (1.0f + erff(v * 0.70710678118654752f));
            ((unsigned short*)outp)[(size_t)row * 256 + col] = f2bf(v);
          }
          if (RES) {
            float xr = resid[(size_t)row * 128 + col];
            ((float*)outp)[(size_t)row * 128 + col] = xr + v;
          }
        }
      }
    }
  }
}

extern "C" void kernel_launch(void* const* d_in, const int* in_sizes, int n_in,
                              void* d_out, int out_size, void* d_ws, size_t ws_size,
                              hipStream_t stream) {
  const float* x    = (const float*)d_in[0];
  const int* esrc   = (const int*)d_in[1];
  const int* edst   = (const int*)d_in[2];
  const float* sn_g = (const float*)d_in[4];
  const float* sn_b = (const float*)d_in[5];
  const float* nn_g = (const float*)d_in[6];
  const float* nn_b = (const float*)d_in[7];
  const float* W1   = (const float*)d_in[8];
  const float* b1   = (const float*)d_in[9];
  const float* W2   = (const float*)d_in[10];
  const float* b2   = (const float*)d_in[11];

  char* ws = (char*)d_ws;
  const size_t H_BYTES = (size_t)TOK * 256 * 2;          // 51.2 MB
  unsigned short* h = (unsigned short*)ws;               // [TOK][256] bf16
  // CSR region (dead before gemm1), aliased by h1:
  char* csr = ws + H_BYTES;
  int* cnt        = (int*)(csr);                          // 50000 ints
  int* part       = (int*)(csr + 200000);                 // 50000 ints
  int* rs         = (int*)(csr + 400000);                 // 50001 ints
  int* cursor     = (int*)(csr + 600016);                 // 50000 ints
  int* bsum       = (int*)(csr + 800016);                 // 49 ints
  int* boff       = (int*)(csr + 800224);                 // 64 ints
  int* sorted_src = (int*)(csr + 800512);                 // 800000 ints
  unsigned short* h1 = (unsigned short*)(ws + H_BYTES);   // aliases CSR
  unsigned short* W1t = (unsigned short*)(ws + 2 * H_BYTES);
  unsigned short* W2t = W1t + 65536;

  hipMemsetAsync(cnt, 0, (size_t)N_ * sizeof(int), stream);
  prep_w_k<<<(98304 + 255) / 256, 256, 0, stream>>>(W1, W2, W1t, W2t);
  hist_k<<<(E_ + 255) / 256, 256, 0, stream>>>(edst, cnt);
  scan1_k<<<49, 1024, 0, stream>>>(cnt, part, bsum);
  scan2_k<<<1, 64, 0, stream>>>(bsum, boff);
  scan3_k<<<49, 1024, 0, stream>>>(part, boff, rs, cursor);
  fill_k<<<(E_ + 255) / 256, 256, 0, stream>>>(esrc, edst, cursor, sorted_src);
  gather_ln_k<<<N_ / 4, 256, 0, stream>>>(x, rs, sorted_src,
                                          sn_g, sn_b, nn_g, nn_b, h);
  dim3 g1((TOK + 127) / 128, 2);
  gemm_k<true, false><<<g1, 256, 0, stream>>>(h, W1t, b1, nullptr, h1, TOK);
  dim3 g2((TOK + 127) / 128, 1);
  gemm_k<false, true><<<g2, 256, 0, stream>>>(h1, W2t, b2, x, d_out, TOK);
}